// Round 4
// baseline (2868.486 us; speedup 1.0000x reference)
//
#include <hip/hip_runtime.h>
#include <hip/hip_bf16.h>

typedef _Float16 f16x8 __attribute__((ext_vector_type(8)));
typedef float f32x4 __attribute__((ext_vector_type(4)));

#define BATCH 256
#define UD 128
#define K1 512
#define LDA 520    // 512 + 8 f16 pad
#define LDA2 392   // 384 + 8 f16 pad
#define CELLSZ (BATCH*UD)          // floats per grid cell
#define RINGSZ (32*CELLSZ)         // one diagonal slot: 32 cells

// inputs (B,C,32,32) fp32 -> X[(i*32+j)][b][c] f16  (LDS transpose, coalesced both sides)
__global__ void k_reorder(const float* __restrict__ in, _Float16* __restrict__ X){
  int b = blockIdx.x, i = blockIdx.y;
  __shared__ float tile[128][33];
  int tid = threadIdx.x;
#pragma unroll
  for (int r=0;r<16;++r){
    int c = r*8 + (tid>>5), j = tid&31;
    tile[c][j] = in[(((size_t)b*128 + c)*32 + i)*32 + j];
  }
  __syncthreads();
#pragma unroll
  for (int r=0;r<16;++r){
    int j = r*2 + (tid>>7), c = tid&127;
    X[((size_t)(i*32 + j)*256 + b)*128 + c] = (_Float16)tile[c][j];
  }
}

// WT[n][k] = W[k][n]; B2T[n][k] = (k<384 ? Umat[k][n] : w_ij[k-384][n])  (fp32 -> f16)
__global__ void k_prep(const float* __restrict__ W,
                       const float* __restrict__ Um,
                       const float* __restrict__ wij,
                       _Float16* __restrict__ WT, _Float16* __restrict__ B2T){
  int idx = blockIdx.x*256 + threadIdx.x;
  if (idx < 896*512){
    int n = idx >> 9, k = idx & 511;
    WT[idx] = (_Float16)W[k*896 + n];
  }
  if (idx < 128*512){
    int n = idx >> 9, k = idx & 511;
    float v = (k < 384) ? Um[k*128 + n] : wij[(k-384)*128 + n];
    B2T[idx] = (_Float16)v;
  }
}

// final h(31,31) lives in ring slot 62%3==2, cell index i=31. OUTPUT IS FP32
// (R3 post-mortem: reference output dtype is float32; writing bf16 packed two
// halves per fp32 slot and left the upper half of d_out as memset-zero).
__global__ void k_out(const float* __restrict__ ring, float* __restrict__ out){
  int t = blockIdx.x*256 + threadIdx.x;
  out[t] = ring[(size_t)2*RINGSZ + (size_t)31*CELLSZ + t];
}

// One diagonal step. Block = (cell index i on diagonal, 32-row batch strip). 4 waves.
// Ring: slot d%3 holds diagonal d, indexed by i. left=(d-1,i), top=(d-1,i-1), diag=(d-2,i-1).
// A layout (k): [0:128)=h_top [128:256)=h_left [256:384)=h_diag [384:512)=s_ij  (= W row order)
// GEMM1 n: [0:384)=r, [384:896)=z (zi,zl,zt,zd groups of 128)
// A2 (k): [r0*h_left | r1*h_top | r2*h_diag | s_ij]  (= [Umat;w_ij] row order)
__global__ __launch_bounds__(256, 2) void k_diag(
    int d,
    const _Float16* __restrict__ X,
    float* __restrict__ ring,
    const _Float16* __restrict__ WT,
    const _Float16* __restrict__ B2T,
    const float* __restrict__ bias)
{
  __shared__ __align__(16) _Float16 Al[32*LDA];
  __shared__ __align__(16) _Float16 A2l[32*LDA2];

  const int i0 = (d > 31) ? (d - 31) : 0;
  const int i = i0 + blockIdx.x;
  const int j = d - i;
  const int bs = blockIdx.y * 32;

  const int tid  = threadIdx.x;
  const int wave = tid >> 6;
  const int lane = tid & 63;
  const int l15  = lane & 15;
  const int quad = lane >> 4;

  const bool hasT = (i >= 1);
  const bool hasL = (j >= 1);
  const bool hasD = hasT && hasL;

  const float* rm1 = ring + (size_t)((d+2)%3)*RINGSZ;   // diagonal d-1
  const float* rm2 = ring + (size_t)((d+1)%3)*RINGSZ;   // diagonal d-2
  float*       rw  = ring + (size_t)(d%3)*RINGSZ;       // diagonal d

  const float* hTop  = rm1 + (size_t)(i-1)*CELLSZ;
  const float* hLeft = rm1 + (size_t)i*CELLSZ;
  const float* hDiag = rm2 + (size_t)(i-1)*CELLSZ;
  float*       hOut  = rw  + (size_t)i*CELLSZ;
  const _Float16* Xc = X + (size_t)(i*32 + j)*CELLSZ;

  // ---- stage A (32 x 512 f16) into LDS; absent neighbors -> zeros
  {
    const float* srcs[3];
    srcs[0] = hasT ? hTop : nullptr;
    srcs[1] = hasL ? hLeft : nullptr;
    srcs[2] = hasD ? hDiag : nullptr;
#pragma unroll
    for (int r=0;r<3;++r){
      const float* src = srcs[r];
      if (src){
        for (int v = tid; v < 1024; v += 256){
          int m = v >> 5, kc = (v & 31) << 2;
          float4 f = *(const float4*)(src + (size_t)(bs+m)*UD + kc);
          union { _Float16 h[4]; ushort4 u; } p;
          p.h[0]=(_Float16)f.x; p.h[1]=(_Float16)f.y;
          p.h[2]=(_Float16)f.z; p.h[3]=(_Float16)f.w;
          *(ushort4*)&Al[m*LDA + r*128 + kc] = p.u;
        }
      } else {
        for (int v = tid; v < 1024; v += 256){
          int m = v >> 5, kc = (v & 31) << 2;
          *(ushort4*)&Al[m*LDA + r*128 + kc] = make_ushort4(0,0,0,0);
        }
      }
    }
    for (int v = tid; v < 512; v += 256){
      int m = v >> 4, kc = (v & 15) << 3;
      *(uint4*)&Al[m*LDA + 384 + kc] = *(const uint4*)(Xc + (size_t)(bs+m)*UD + kc);
    }
  }
  __syncthreads();

  // ---- GEMM1: (32 x 512) @ (512 x 896). Wave owns 224 n-cols:
  // tiles 0..5: r cols wave*96 + t*16 ; tiles 6..13: z gate g=(t-6)>>1, sub=(t-6)&1
  f32x4 acc[2][14];
#pragma unroll
  for (int a=0;a<2;++a)
#pragma unroll
    for (int t=0;t<14;++t) acc[a][t] = (f32x4){0.f,0.f,0.f,0.f};

#pragma unroll
  for (int ks=0; ks<16; ++ks){
    const int kb = ks*32 + quad*8;
    f16x8 a0 = *(const f16x8*)&Al[l15*LDA + kb];
    f16x8 a1 = *(const f16x8*)&Al[(16+l15)*LDA + kb];
#pragma unroll
    for (int t=0;t<14;++t){
      const int n = (t<6) ? (wave*96 + t*16)
                          : (384 + ((t-6)>>1)*128 + wave*32 + ((t-6)&1)*16);
      f16x8 b = *(const f16x8*)&WT[(size_t)(n + l15)*K1 + kb];
      acc[0][t] = __builtin_amdgcn_mfma_f32_16x16x32_f16(a0, b, acc[0][t], 0,0,0);
      acc[1][t] = __builtin_amdgcn_mfma_f32_16x16x32_f16(a1, b, acc[1][t], 0,0,0);
    }
  }

  // ---- r = hard_sigmoid(.); A2 = r * h (re-ordered), f16 into LDS
#pragma unroll
  for (int mt=0;mt<2;++mt)
#pragma unroll
    for (int t=0;t<6;++t){
      const int col = wave*96 + t*16 + l15;
      const float br = bias[col];
      // r col <128 multiplies h_left (Al k=128+col); 128..255 -> h_top (col-128); 256..383 -> h_diag (col)
      const int hcol = (col < 128) ? (128 + col) : ((col < 256) ? (col - 128) : col);
#pragma unroll
      for (int rg=0;rg<4;++rg){
        const int m = mt*16 + quad*4 + rg;
        float r = 0.2f*(acc[mt][t][rg] + br) + 0.5f;
        r = fminf(fmaxf(r, 0.f), 1.f);
        float h = (float)Al[m*LDA + hcol];
        A2l[m*LDA2 + col] = (_Float16)(r*h);
      }
    }
  __syncthreads();

  // ---- GEMM2: (32 x 512) @ (512 x 128); k>=384 (s_ij) read from Al
  f32x4 acc2[2][2];
#pragma unroll
  for (int a=0;a<2;++a){ acc2[a][0]=(f32x4){0.f,0.f,0.f,0.f}; acc2[a][1]=(f32x4){0.f,0.f,0.f,0.f}; }
#pragma unroll
  for (int ks=0; ks<16; ++ks){
    const int kb = ks*32 + quad*8;
    f16x8 a0, a1;
    if (ks < 12){
      a0 = *(const f16x8*)&A2l[l15*LDA2 + kb];
      a1 = *(const f16x8*)&A2l[(16+l15)*LDA2 + kb];
    } else {
      a0 = *(const f16x8*)&Al[l15*LDA + kb];
      a1 = *(const f16x8*)&Al[(16+l15)*LDA + kb];
    }
#pragma unroll
    for (int s=0;s<2;++s){
      f16x8 b = *(const f16x8*)&B2T[(size_t)(wave*32 + s*16 + l15)*K1 + kb];
      acc2[0][s] = __builtin_amdgcn_mfma_f32_16x16x32_f16(a0, b, acc2[0][s], 0,0,0);
      acc2[1][s] = __builtin_amdgcn_mfma_f32_16x16x32_f16(a1, b, acc2[1][s], 0,0,0);
    }
  }

  // ---- softmax over 4 z-gates, tanh candidate, combine (fp32 carry), store h fp32
#pragma unroll
  for (int mt=0;mt<2;++mt)
#pragma unroll
    for (int s=0;s<2;++s){
      const int u = wave*32 + s*16 + l15;
      const float bz0 = bias[384 + 0*128 + u];
      const float bz1 = bias[384 + 1*128 + u];
      const float bz2 = bias[384 + 2*128 + u];
      const float bz3 = bias[384 + 3*128 + u];
      const float bij = bias[896 + u];
#pragma unroll
      for (int rg=0;rg<4;++rg){
        const int m = mt*16 + quad*4 + rg;
        const size_t row = (size_t)(bs+m)*UD + u;
        float z0 = acc[mt][6 + 0 + s][rg] + bz0;  // zi
        float z1 = acc[mt][6 + 2 + s][rg] + bz1;  // zl
        float z2 = acc[mt][6 + 4 + s][rg] + bz2;  // zt
        float z3 = acc[mt][6 + 6 + s][rg] + bz3;  // zd
        float mx = fmaxf(fmaxf(z0,z1), fmaxf(z2,z3));
        float e0 = __expf(z0-mx), e1 = __expf(z1-mx), e2 = __expf(z2-mx), e3 = __expf(z3-mx);
        float inv = 1.f/(e0+e1+e2+e3);
        float hl = hasL ? hLeft[row] : 0.f;
        float ht = hasT ? hTop[row]  : 0.f;
        float hd = hasD ? hDiag[row] : 0.f;
        float cand = tanhf(acc2[mt][s][rg] + bij);
        hOut[row] = (e1*hl + e2*ht + e3*hd + e0*cand)*inv;
      }
    }
}

extern "C" void kernel_launch(void* const* d_in, const int* in_sizes, int n_in,
                              void* d_out, int out_size, void* d_ws, size_t ws_size,
                              hipStream_t stream){
  // Inputs fp32 (R2 post-mortem: bf16 reads of these buffers produced NaN).
  // Output fp32 (R3 post-mortem: reference output dtype is float32).
  const float* inp  = (const float*)d_in[0]; // (256,128,32,32) f32
  const float* W    = (const float*)d_in[1]; // (512,896) f32
  const float* Um   = (const float*)d_in[2]; // (384,128) f32
  const float* bias = (const float*)d_in[3]; // (1024,)  f32
  const float* wij  = (const float*)d_in[4]; // (128,128) f32
  float* out = (float*)d_out;                // (256,128) f32

  // Workspace (80.7 MB):
  //   WT   @ 0          : 896*512*2       =    917,504 B
  //   B2T  @ 917,504    : 128*512*2       =    131,072 B
  //   X    @ 1,048,576  : 1024*256*128*2  = 67,108,864 B
  //   ring @ 68,157,440 : 3*32*256*128*4  = 12,582,912 B   (end 80,740,352)
  char* ws = (char*)d_ws;
  _Float16* WT   = (_Float16*)(ws);
  _Float16* B2T  = (_Float16*)(ws + 917504);
  _Float16* X    = (_Float16*)(ws + 1048576);
  float*    ring = (float*)   (ws + 68157440);

  k_reorder<<<dim3(256,32),256,0,stream>>>(inp, X);
  k_prep<<<1792,256,0,stream>>>(W, Um, wij, WT, B2T);
  for (int d=0; d<63; ++d){
    int ilo = (d>31)?(d-31):0, ihi = (d<31)?d:31;
    int nc = ihi - ilo + 1;
    k_diag<<<dim3(nc,8),256,0,stream>>>(d, X, ring, WT, B2T, bias);
  }
  k_out<<<128,256,0,stream>>>(ring, out);
}

// Round 5
// 2776.250 us; speedup vs baseline: 1.0332x; 1.0332x over previous
//
#include <hip/hip_runtime.h>
#include <hip/hip_bf16.h>

typedef _Float16 f16x8 __attribute__((ext_vector_type(8)));
typedef float f32x4 __attribute__((ext_vector_type(4)));

#define BATCH 256
#define UD 128
#define K1 512
#define LDA 520    // 512 + 8 f16 pad
#define LDA2 392   // 384 + 8 f16 pad
#define CELLSZ (BATCH*UD)          // floats per grid cell
#define RINGSZ (32*CELLSZ)         // one diagonal slot: 32 cells

// inputs (B,C,32,32) fp32 -> X[(i*32+j)][b][c] f16  (LDS transpose, coalesced both sides)
__global__ void k_reorder(const float* __restrict__ in, _Float16* __restrict__ X){
  int b = blockIdx.x, i = blockIdx.y;
  __shared__ float tile[128][33];
  int tid = threadIdx.x;
#pragma unroll
  for (int r=0;r<16;++r){
    int c = r*8 + (tid>>5), j = tid&31;
    tile[c][j] = in[(((size_t)b*128 + c)*32 + i)*32 + j];
  }
  __syncthreads();
#pragma unroll
  for (int r=0;r<16;++r){
    int j = r*2 + (tid>>7), c = tid&127;
    X[((size_t)(i*32 + j)*256 + b)*128 + c] = (_Float16)tile[c][j];
  }
}

// WT[n][k] = W[k][n]; B2T[n][k] = (k<384 ? Umat[k][n] : w_ij[k-384][n])  (fp32 -> f16)
__global__ void k_prep(const float* __restrict__ W,
                       const float* __restrict__ Um,
                       const float* __restrict__ wij,
                       _Float16* __restrict__ WT, _Float16* __restrict__ B2T){
  int idx = blockIdx.x*256 + threadIdx.x;
  if (idx < 896*512){
    int n = idx >> 9, k = idx & 511;
    WT[idx] = (_Float16)W[k*896 + n];
  }
  if (idx < 128*512){
    int n = idx >> 9, k = idx & 511;
    float v = (k < 384) ? Um[k*128 + n] : wij[(k-384)*128 + n];
    B2T[idx] = (_Float16)v;
  }
}

// final h(31,31) lives in ring slot 62%3==2, cell index i=31. Output fp32.
__global__ void k_out(const float* __restrict__ ring, float* __restrict__ out){
  int t = blockIdx.x*256 + threadIdx.x;
  out[t] = ring[(size_t)2*RINGSZ + (size_t)31*CELLSZ + t];
}

// One diagonal step. Block = (cell index i on diagonal, 32-row batch strip). 4 waves.
// Ring: slot d%3 holds diagonal d, indexed by i. left=(d-1,i), top=(d-1,i-1), diag=(d-2,i-1).
// A layout (k): [0:128)=h_top [128:256)=h_left [256:384)=h_diag [384:512)=s_ij  (= W row order)
// GEMM1 n: [0:384)=r, [384:896)=z (zi,zl,zt,zd groups of 128)
// A2 (k): [r0*h_left | r1*h_top | r2*h_diag | s_ij]  (= [Umat;w_ij] row order)
//
// R4 post-mortem: __launch_bounds__(256,2) capped VGPRs at 256 while the kernel
// wants ~220+ live regs -> spill/no-ILP on the 14 B-fragment loads per K-step.
// Wide diagonals never exceed 256 blocks = 1 block/CU, so 2-block occupancy was
// pure loss. Now (256,1) = 512-reg cap + explicit B double-buffering.
__global__ __launch_bounds__(256, 1) void k_diag(
    int d,
    const _Float16* __restrict__ X,
    float* __restrict__ ring,
    const _Float16* __restrict__ WT,
    const _Float16* __restrict__ B2T,
    const float* __restrict__ bias)
{
  __shared__ __align__(16) _Float16 Al[32*LDA];
  __shared__ __align__(16) _Float16 A2l[32*LDA2];

  const int i0 = (d > 31) ? (d - 31) : 0;
  const int i = i0 + blockIdx.x;
  const int j = d - i;
  const int bs = blockIdx.y * 32;

  const int tid  = threadIdx.x;
  const int wave = tid >> 6;
  const int lane = tid & 63;
  const int l15  = lane & 15;
  const int quad = lane >> 4;

  const bool hasT = (i >= 1);
  const bool hasL = (j >= 1);
  const bool hasD = hasT && hasL;

  const float* rm1 = ring + (size_t)((d+2)%3)*RINGSZ;   // diagonal d-1
  const float* rm2 = ring + (size_t)((d+1)%3)*RINGSZ;   // diagonal d-2
  float*       rw  = ring + (size_t)(d%3)*RINGSZ;       // diagonal d

  const float* hTop  = rm1 + (size_t)(i-1)*CELLSZ;
  const float* hLeft = rm1 + (size_t)i*CELLSZ;
  const float* hDiag = rm2 + (size_t)(i-1)*CELLSZ;
  float*       hOut  = rw  + (size_t)i*CELLSZ;
  const _Float16* Xc = X + (size_t)(i*32 + j)*CELLSZ;

  // ---- stage A (32 x 512 f16) into LDS; absent neighbors -> zeros
  {
    const float* srcs[3];
    srcs[0] = hasT ? hTop : nullptr;
    srcs[1] = hasL ? hLeft : nullptr;
    srcs[2] = hasD ? hDiag : nullptr;
#pragma unroll
    for (int r=0;r<3;++r){
      const float* src = srcs[r];
      if (src){
        for (int v = tid; v < 1024; v += 256){
          int m = v >> 5, kc = (v & 31) << 2;
          float4 f = *(const float4*)(src + (size_t)(bs+m)*UD + kc);
          union { _Float16 h[4]; ushort4 u; } p;
          p.h[0]=(_Float16)f.x; p.h[1]=(_Float16)f.y;
          p.h[2]=(_Float16)f.z; p.h[3]=(_Float16)f.w;
          *(ushort4*)&Al[m*LDA + r*128 + kc] = p.u;
        }
      } else {
        for (int v = tid; v < 1024; v += 256){
          int m = v >> 5, kc = (v & 31) << 2;
          *(ushort4*)&Al[m*LDA + r*128 + kc] = make_ushort4(0,0,0,0);
        }
      }
    }
    for (int v = tid; v < 512; v += 256){
      int m = v >> 4, kc = (v & 15) << 3;
      *(uint4*)&Al[m*LDA + 384 + kc] = *(const uint4*)(Xc + (size_t)(bs+m)*UD + kc);
    }
  }
  __syncthreads();

  // ---- GEMM1: (32 x 512) @ (512 x 896). Wave owns 224 n-cols:
  // tiles 0..5: r cols wave*96 + t*16 ; tiles 6..13: z gate g=(t-6)>>1, sub=(t-6)&1
  f32x4 acc[2][14];
#pragma unroll
  for (int a=0;a<2;++a)
#pragma unroll
    for (int t=0;t<14;++t) acc[a][t] = (f32x4){0.f,0.f,0.f,0.f};

  {
    const _Float16* bptr[14];
#pragma unroll
    for (int t=0;t<14;++t){
      const int n = (t<6) ? (wave*96 + t*16)
                          : (384 + ((t-6)>>1)*128 + wave*32 + ((t-6)&1)*16);
      bptr[t] = WT + (size_t)(n + l15)*K1 + quad*8;
    }
    f16x8 bcur[14], bnxt[14];
#pragma unroll
    for (int t=0;t<14;++t) bcur[t] = *(const f16x8*)(bptr[t]);
#pragma unroll
    for (int ks=0; ks<16; ++ks){
      const int kb = ks*32 + quad*8;
      if (ks < 15){
#pragma unroll
        for (int t=0;t<14;++t) bnxt[t] = *(const f16x8*)(bptr[t] + (ks+1)*32);
      }
      f16x8 a0 = *(const f16x8*)&Al[l15*LDA + kb];
      f16x8 a1 = *(const f16x8*)&Al[(16+l15)*LDA + kb];
#pragma unroll
      for (int t=0;t<14;++t){
        acc[0][t] = __builtin_amdgcn_mfma_f32_16x16x32_f16(a0, bcur[t], acc[0][t], 0,0,0);
        acc[1][t] = __builtin_amdgcn_mfma_f32_16x16x32_f16(a1, bcur[t], acc[1][t], 0,0,0);
      }
#pragma unroll
      for (int t=0;t<14;++t) bcur[t] = bnxt[t];
    }
  }

  // ---- r = hard_sigmoid(.); A2 = r * h (re-ordered), f16 into LDS
#pragma unroll
  for (int mt=0;mt<2;++mt)
#pragma unroll
    for (int t=0;t<6;++t){
      const int col = wave*96 + t*16 + l15;
      const float br = bias[col];
      // r col <128 multiplies h_left (Al k=128+col); 128..255 -> h_top (col-128); 256..383 -> h_diag (col)
      const int hcol = (col < 128) ? (128 + col) : ((col < 256) ? (col - 128) : col);
#pragma unroll
      for (int rg=0;rg<4;++rg){
        const int m = mt*16 + quad*4 + rg;
        float r = 0.2f*(acc[mt][t][rg] + br) + 0.5f;
        r = fminf(fmaxf(r, 0.f), 1.f);
        float h = (float)Al[m*LDA + hcol];
        A2l[m*LDA2 + col] = (_Float16)(r*h);
      }
    }
  __syncthreads();

  // ---- GEMM2: (32 x 512) @ (512 x 128); k>=384 (s_ij) read from Al
  f32x4 acc2[2][2];
#pragma unroll
  for (int a=0;a<2;++a){ acc2[a][0]=(f32x4){0.f,0.f,0.f,0.f}; acc2[a][1]=(f32x4){0.f,0.f,0.f,0.f}; }
  {
    const _Float16* b2ptr[2];
#pragma unroll
    for (int s=0;s<2;++s) b2ptr[s] = B2T + (size_t)(wave*32 + s*16 + l15)*K1 + quad*8;
    f16x8 b2cur[2], b2nxt[2];
#pragma unroll
    for (int s=0;s<2;++s) b2cur[s] = *(const f16x8*)(b2ptr[s]);
#pragma unroll
    for (int ks=0; ks<16; ++ks){
      const int kb = ks*32 + quad*8;
      if (ks < 15){
#pragma unroll
        for (int s=0;s<2;++s) b2nxt[s] = *(const f16x8*)(b2ptr[s] + (ks+1)*32);
      }
      f16x8 a0, a1;
      if (ks < 12){
        a0 = *(const f16x8*)&A2l[l15*LDA2 + kb];
        a1 = *(const f16x8*)&A2l[(16+l15)*LDA2 + kb];
      } else {
        a0 = *(const f16x8*)&Al[l15*LDA + kb];
        a1 = *(const f16x8*)&Al[(16+l15)*LDA + kb];
      }
#pragma unroll
      for (int s=0;s<2;++s){
        acc2[0][s] = __builtin_amdgcn_mfma_f32_16x16x32_f16(a0, b2cur[s], acc2[0][s], 0,0,0);
        acc2[1][s] = __builtin_amdgcn_mfma_f32_16x16x32_f16(a1, b2cur[s], acc2[1][s], 0,0,0);
      }
#pragma unroll
      for (int s=0;s<2;++s) b2cur[s] = b2nxt[s];
    }
  }

  // ---- softmax over 4 z-gates, tanh candidate, combine (fp32 carry), store h fp32
#pragma unroll
  for (int mt=0;mt<2;++mt)
#pragma unroll
    for (int s=0;s<2;++s){
      const int u = wave*32 + s*16 + l15;
      const float bz0 = bias[384 + 0*128 + u];
      const float bz1 = bias[384 + 1*128 + u];
      const float bz2 = bias[384 + 2*128 + u];
      const float bz3 = bias[384 + 3*128 + u];
      const float bij = bias[896 + u];
#pragma unroll
      for (int rg=0;rg<4;++rg){
        const int m = mt*16 + quad*4 + rg;
        const size_t row = (size_t)(bs+m)*UD + u;
        float z0 = acc[mt][6 + 0 + s][rg] + bz0;  // zi
        float z1 = acc[mt][6 + 2 + s][rg] + bz1;  // zl
        float z2 = acc[mt][6 + 4 + s][rg] + bz2;  // zt
        float z3 = acc[mt][6 + 6 + s][rg] + bz3;  // zd
        float mx = fmaxf(fmaxf(z0,z1), fmaxf(z2,z3));
        float e0 = __expf(z0-mx), e1 = __expf(z1-mx), e2 = __expf(z2-mx), e3 = __expf(z3-mx);
        float inv = 1.f/(e0+e1+e2+e3);
        float hl = hasL ? hLeft[row] : 0.f;
        float ht = hasT ? hTop[row]  : 0.f;
        float hd = hasD ? hDiag[row] : 0.f;
        float cand = tanhf(acc2[mt][s][rg] + bij);
        hOut[row] = (e1*hl + e2*ht + e3*hd + e0*cand)*inv;
      }
    }
}

extern "C" void kernel_launch(void* const* d_in, const int* in_sizes, int n_in,
                              void* d_out, int out_size, void* d_ws, size_t ws_size,
                              hipStream_t stream){
  // Inputs fp32; output fp32 (R2/R3 post-mortems).
  const float* inp  = (const float*)d_in[0]; // (256,128,32,32) f32
  const float* W    = (const float*)d_in[1]; // (512,896) f32
  const float* Um   = (const float*)d_in[2]; // (384,128) f32
  const float* bias = (const float*)d_in[3]; // (1024,)  f32
  const float* wij  = (const float*)d_in[4]; // (128,128) f32
  float* out = (float*)d_out;                // (256,128) f32

  // Workspace (80.7 MB):
  //   WT   @ 0          : 896*512*2       =    917,504 B
  //   B2T  @ 917,504    : 128*512*2       =    131,072 B
  //   X    @ 1,048,576  : 1024*256*128*2  = 67,108,864 B
  //   ring @ 68,157,440 : 3*32*256*128*4  = 12,582,912 B   (end 80,740,352)
  char* ws = (char*)d_ws;
  _Float16* WT   = (_Float16*)(ws);
  _Float16* B2T  = (_Float16*)(ws + 917504);
  _Float16* X    = (_Float16*)(ws + 1048576);
  float*    ring = (float*)   (ws + 68157440);

  k_reorder<<<dim3(256,32),256,0,stream>>>(inp, X);
  k_prep<<<1792,256,0,stream>>>(W, Um, wij, WT, B2T);
  for (int d=0; d<63; ++d){
    int ilo = (d>31)?(d-31):0, ihi = (d<31)?d:31;
    int nc = ihi - ilo + 1;
    k_diag<<<dim3(nc,8),256,0,stream>>>(d, X, ring, WT, B2T, bias);
  }
  k_out<<<128,256,0,stream>>>(ring, out);
}